// Round 5
// baseline (910.594 us; speedup 1.0000x reference)
//
#include <hip/hip_runtime.h>
#include <hip/hip_bf16.h>

#define KP    32
#define NIN_  64
#define RNK   16
#define NOUT_ 128
#define HID_  64
#define CDIM  1024   // RNK*NIN_
#define EPS_  1e-7f
#define LNEPS 1e-5f
#define NTOT  16384  // B*N

using short8 = __attribute__((ext_vector_type(8))) short;
using f32x4  = __attribute__((ext_vector_type(4))) float;

__device__ __forceinline__ unsigned short f2bf(float x) {
  unsigned u = __float_as_uint(x);
  return (unsigned short)((u + 0x7fffu + ((u >> 16) & 1u)) >> 16);
}

// ---------------- prep: woT[n][k] = bf16(wo[k][n]) ----------------
__global__ __launch_bounds__(256) void k0_woT(const float* __restrict__ wo,
                                              unsigned short* __restrict__ woT) {
  __shared__ unsigned short S[64][129];
  const int t = threadIdx.x;
  const int k0 = blockIdx.x * 64;
  #pragma unroll
  for (int i = 0; i < 32; ++i) {
    const int idx = i * 256 + t;
    const int k = idx >> 7, n = idx & 127;
    S[k][n] = f2bf(wo[(long)(k0 + k) * NOUT_ + n]);
  }
  __syncthreads();
  #pragma unroll
  for (int i = 0; i < 32; ++i) {
    const int idx = i * 256 + t;
    const int n = idx >> 6, k = idx & 63;
    woT[(long)n * CDIM + k0 + k] = S[k][n];
  }
}

// ---------------- k1: geometry + MLPs (VALU) + contraction (MFMA) ----------
// 256 thr = 4 waves, each wave 2 points (grid 2048), wave-synchronous (no
// barriers in the point loop; per-wave LDS, DS pipe is in-order per wave).
// Phases A-C lane layout: lane = 2*kk + hh. Phase D: one MFMA per 16-col.
// featT[i][k] bf16, row stride 40 elems (80B, 16B-multiple), chunk-XOR swizzle.
__global__ __launch_bounds__(256, 3) void k1_contract(
    const float* __restrict__ fp,   // (NTOT, KP, 3)
    const float* __restrict__ feat, // (NTOT, KP, NIN_)
    const float* __restrict__ ep,   // (NTOT, 3)
    const float* __restrict__ w1,   // (8, HID_)
    const float* __restrict__ b1, const float* __restrict__ g1,
    const float* __restrict__ be1,
    const float* __restrict__ w2,   // (HID_, RNK)
    const float* __restrict__ b2,
    unsigned short* __restrict__ A) // (NTOT, CDIM) bf16
{
  __shared__ float w1T[64][8];           // w1T[h][x] = w1[x][h]
  __shared__ float w2S[64][16];
  __shared__ float b1S[64], g1S[64], beS[64], b2S[16];
  __shared__ __align__(16) unsigned short featT[4][64 * 40]; // [wv][i*40 + k]
  __shared__ __align__(16) unsigned short kernT[4][16 * 40]; // [wv][r*40 + k]

  const int t = threadIdx.x;
  const int wv = t >> 6, lane = t & 63;
  const int hh = lane & 1, kk = lane >> 1;

  if (t < 64) {
    #pragma unroll
    for (int x = 0; x < 8; ++x) w1T[t][x] = w1[x * HID_ + t];
    b1S[t] = b1[t]; g1S[t] = g1[t]; beS[t] = be1[t];
  }
  reinterpret_cast<float4*>(&w2S[0][0])[t] = reinterpret_cast<const float4*>(w2)[t];
  if (t < 16) b2S[t] = b2[t];
  __syncthreads();

  #pragma unroll 1
  for (int pi = 0; pi < 2; ++pi) {
    const long pt = (long)blockIdx.x * 8 + wv * 2 + pi;

    // issue feat column loads early (lane owns col i = lane); coalesced rows
    const float* fcol = feat + pt * (KP * NIN_) + lane;
    float fr[32];
    #pragma unroll
    for (int k = 0; k < 32; ++k) fr[k] = fcol[k * 64];

    // ---- phase A: geometry for neighbor kk (lane pairs redundant) ----
    const float* prp = fp + (pt * KP + kk) * 3;
    const float prx = prp[0], pry = prp[1], prz = prp[2];
    const float* psp = ep + pt * 3;
    const float psx = psp[0], psy = psp[1], psz = psp[2];

    float sx = prx, sy = pry, sz = prz;
    #pragma unroll
    for (int m = 2; m <= 32; m <<= 1) {
      sx += __shfl_xor(sx, m); sy += __shfl_xor(sy, m); sz += __shfl_xor(sz, m);
    }
    const float inv = 1.f / 32.f;
    const float mx = sx * inv, my = sy * inv, mz = sz * inv;

    const float l1x = mx - prx, l1y = my - pry, l1z = mz - prz;
    const float l2x = prx - psx, l2y = pry - psy, l2z = prz - psz;
    const float l3x = psx - mx, l3y = psy - my, l3z = psz - mz;
    const float l1n = sqrtf(l1x * l1x + l1y * l1y + l1z * l1z);
    const float l2n = sqrtf(l2x * l2x + l2y * l2y + l2z * l2z);
    const float l3n = sqrtf(l3x * l3x + l3y * l3y + l3z * l3z);
    const float th1 = (l1x * l2x + l1y * l2y + l1z * l2z) / (l1n * l2n + EPS_);
    const float th2 = (l2x * l3x + l2y * l3y + l2z * l3z) / (l2n * l3n + EPS_);
    const float th3 = (l3x * l1x + l3y * l1y + l3z * l1z) / (l3n * l1n + EPS_);
    const float hn  = sqrtf(prx * prx + pry * pry + prz * prz);
    const float psn = sqrtf(psx * psx + psy * psy + psz * psz);
    float cc = (psx * prx + psy * pry + psz * prz) / (psn * hn);
    cc = fminf(1.f, fmaxf(-1.f, cc));
    const float ri0 = acosf(cc) * 0.31830988618379067f;
    const float ri1 = hn,  ri2 = l1n, ri3 = l2n;
    const float ri4 = l3n, ri5 = th1, ri6 = th2, ri7 = th3;

    // ---- phase B: vals = relu(LN(ri @ w1 + b1)), lane-pair LN over 64 ----
    float vals[32];
    #pragma unroll
    for (int j = 0; j < 32; ++j) {
      const int h = hh * 32 + j;
      const float4 wa = *reinterpret_cast<const float4*>(&w1T[h][0]);
      const float4 wb = *reinterpret_cast<const float4*>(&w1T[h][4]);
      vals[j] = b1S[h]
        + ri0 * wa.x + ri1 * wa.y + ri2 * wa.z + ri3 * wa.w
        + ri4 * wb.x + ri5 * wb.y + ri6 * wb.z + ri7 * wb.w;
    }
    float s = 0.f;
    #pragma unroll
    for (int j = 0; j < 32; ++j) s += vals[j];
    s += __shfl_xor(s, 1);
    const float mu = s * (1.f / 64.f);
    float v2 = 0.f;
    #pragma unroll
    for (int j = 0; j < 32; ++j) { const float d = vals[j] - mu; v2 += d * d; }
    v2 += __shfl_xor(v2, 1);
    const float rstd = rsqrtf(v2 * (1.f / 64.f) + LNEPS);
    #pragma unroll
    for (int j = 0; j < 32; ++j) {
      const int h = hh * 32 + j;
      vals[j] = fmaxf((vals[j] - mu) * rstd * g1S[h] + beS[h], 0.f);
    }

    // ---- phase C: kern[r] = b2[r] + sum_h hdn[h]*w2[h][r] ----
    float kern[16];
    #pragma unroll
    for (int r = 0; r < 16; ++r) kern[r] = 0.f;
    #pragma unroll
    for (int j = 0; j < 32; ++j) {
      const int h = hh * 32 + j;
      const float hv = vals[j];
      #pragma unroll
      for (int rc = 0; rc < 4; ++rc) {
        const float4 wr = *reinterpret_cast<const float4*>(&w2S[h][rc * 4]);
        kern[rc * 4 + 0] += hv * wr.x;
        kern[rc * 4 + 1] += hv * wr.y;
        kern[rc * 4 + 2] += hv * wr.z;
        kern[rc * 4 + 3] += hv * wr.w;
      }
    }
    #pragma unroll
    for (int r = 0; r < 16; ++r) kern[r] += __shfl_xor(kern[r], 1);

    // write kernT[r][kk] bf16 (lane 2kk+hh writes r = hh*8+q)
    #pragma unroll
    for (int q = 0; q < 8; ++q) {
      const int r = hh * 8 + q;
      const int byte = r * 80 + ((((kk >> 3) ^ ((r >> 2) & 3)) << 4)) + (kk & 7) * 2;
      *reinterpret_cast<unsigned short*>(
          reinterpret_cast<char*>(&kernT[wv][0]) + byte) = f2bf(kern[r] + b2S[r]);
    }

    // featT write: lane owns row i = lane; pack k-pairs, 4x ds_write_b128
    unsigned int pk[16];
    #pragma unroll
    for (int m2 = 0; m2 < 16; ++m2)
      pk[m2] = (unsigned)f2bf(fr[2 * m2]) | ((unsigned)f2bf(fr[2 * m2 + 1]) << 16);
    #pragma unroll
    for (int c = 0; c < 4; ++c) {
      const int byte = lane * 80 + ((c ^ ((lane >> 2) & 3)) << 4);
      *reinterpret_cast<uint4*>(reinterpret_cast<char*>(&featT[wv][0]) + byte) =
          make_uint4(pk[4 * c], pk[4 * c + 1], pk[4 * c + 2], pk[4 * c + 3]);
    }

    // ---- phase D: cont[r][i] via 4x MFMA (K=32 in one instruction) ----
    const int g = lane >> 4, c16 = lane & 15;
    const short8 afr = *reinterpret_cast<const short8*>(
        reinterpret_cast<const char*>(&kernT[wv][0]) +
        c16 * 80 + ((g ^ ((c16 >> 2) & 3)) << 4));
    f32x4 acc[4];
    #pragma unroll
    for (int nt = 0; nt < 4; ++nt) {
      const int i = nt * 16 + c16;
      const short8 bfr = *reinterpret_cast<const short8*>(
          reinterpret_cast<const char*>(&featT[wv][0]) +
          i * 80 + ((g ^ ((i >> 2) & 3)) << 4));
      acc[nt] = __builtin_amdgcn_mfma_f32_16x16x32_bf16(
          afr, bfr, (f32x4){0.f, 0.f, 0.f, 0.f}, 0, 0, 0);
    }

    // store: D col = c16 (i offset), row = 4g+reg (r)
    unsigned short* Ap = A + pt * CDIM;
    #pragma unroll
    for (int nt = 0; nt < 4; ++nt)
      #pragma unroll
      for (int reg = 0; reg < 4; ++reg)
        Ap[(4 * g + reg) * 64 + nt * 16 + c16] = f2bf(acc[nt][reg]);
  }
}

// ---------------- k2: register-direct bf16 MFMA GEMM + bias + LN ------------
// BM=16, grid 1024 (4 blocks/CU). No K-loop LDS: A/B frags straight from
// global (woT = 256 KB, L2-resident). LN epilogue via small Cs.
__global__ __launch_bounds__(256) void k2_gemm_ln(
    const unsigned short* __restrict__ A,    // (NTOT, CDIM) bf16
    const unsigned short* __restrict__ woT,  // (NOUT_, CDIM) bf16
    const float* __restrict__ bwo, const float* __restrict__ gln,
    const float* __restrict__ bln, float* __restrict__ out)
{
  __shared__ float Cs[16 * 132];

  const int t = threadIdx.x;
  const int w = t >> 6, l = t & 63;
  const int m = l & 15, g = l >> 4;
  const long row0 = (long)blockIdx.x * 16;

  const unsigned short* Arow  = A   + (row0 + m) * CDIM + g * 8;
  const unsigned short* Brow0 = woT + (long)(w * 32 +      m) * CDIM + g * 8;
  const unsigned short* Brow1 = woT + (long)(w * 32 + 16 + m) * CDIM + g * 8;

  f32x4 acc0 = {0.f, 0.f, 0.f, 0.f}, acc1 = {0.f, 0.f, 0.f, 0.f};
  #pragma unroll 4
  for (int kb = 0; kb < CDIM; kb += 32) {
    const short8 af = *reinterpret_cast<const short8*>(Arow + kb);
    const short8 b0 = *reinterpret_cast<const short8*>(Brow0 + kb);
    const short8 b1v = *reinterpret_cast<const short8*>(Brow1 + kb);
    acc0 = __builtin_amdgcn_mfma_f32_16x16x32_bf16(af, b0, acc0, 0, 0, 0);
    acc1 = __builtin_amdgcn_mfma_f32_16x16x32_bf16(af, b1v, acc1, 0, 0, 0);
  }

  // scatter: D col = l&15 (n offset), row = 4g+reg (m)
  #pragma unroll
  for (int reg = 0; reg < 4; ++reg) {
    Cs[(4 * g + reg) * 132 + w * 32 +      m] = acc0[reg];
    Cs[(4 * g + reg) * 132 + w * 32 + 16 + m] = acc1[reg];
  }
  __syncthreads();

  // LN over 128 cols: 16 threads per row, 8 cols each
  {
    const int row = t >> 4, q = t & 15;
    float4 v[2];
    #pragma unroll
    for (int i = 0; i < 2; ++i) {
      const float4 cv = *reinterpret_cast<const float4*>(&Cs[row * 132 + q * 8 + i * 4]);
      const float4 bv = *reinterpret_cast<const float4*>(&bwo[q * 8 + i * 4]);
      v[i] = make_float4(cv.x + bv.x, cv.y + bv.y, cv.z + bv.z, cv.w + bv.w);
    }
    float s = v[0].x + v[0].y + v[0].z + v[0].w + v[1].x + v[1].y + v[1].z + v[1].w;
    s += __shfl_xor(s, 1); s += __shfl_xor(s, 2);
    s += __shfl_xor(s, 4); s += __shfl_xor(s, 8);
    const float mu = s * (1.f / 128.f);
    float d2 = 0.f;
    #pragma unroll
    for (int i = 0; i < 2; ++i) {
      const float dx = v[i].x - mu, dy = v[i].y - mu, dz = v[i].z - mu, dw = v[i].w - mu;
      d2 += dx * dx + dy * dy + dz * dz + dw * dw;
    }
    d2 += __shfl_xor(d2, 1); d2 += __shfl_xor(d2, 2);
    d2 += __shfl_xor(d2, 4); d2 += __shfl_xor(d2, 8);
    const float rstd = rsqrtf(d2 * (1.f / 128.f) + LNEPS);
    float* op = out + (row0 + row) * NOUT_ + q * 8;
    #pragma unroll
    for (int i = 0; i < 2; ++i) {
      const float4 gv = *reinterpret_cast<const float4*>(&gln[q * 8 + i * 4]);
      const float4 bv = *reinterpret_cast<const float4*>(&bln[q * 8 + i * 4]);
      float4 o;
      o.x = (v[i].x - mu) * rstd * gv.x + bv.x;
      o.y = (v[i].y - mu) * rstd * gv.y + bv.y;
      o.z = (v[i].z - mu) * rstd * gv.z + bv.z;
      o.w = (v[i].w - mu) * rstd * gv.w + bv.w;
      *reinterpret_cast<float4*>(op + i * 4) = o;
    }
  }
}

extern "C" void kernel_launch(void* const* d_in, const int* in_sizes, int n_in,
                              void* d_out, int out_size, void* d_ws, size_t ws_size,
                              hipStream_t stream) {
  const float* fp   = (const float*)d_in[0];
  const float* feat = (const float*)d_in[1];
  const float* ep   = (const float*)d_in[2];
  const float* w1   = (const float*)d_in[3];
  const float* b1   = (const float*)d_in[4];
  const float* g1   = (const float*)d_in[5];
  const float* be1  = (const float*)d_in[6];
  const float* w2   = (const float*)d_in[7];
  const float* b2   = (const float*)d_in[8];
  const float* wo   = (const float*)d_in[9];
  const float* bwo  = (const float*)d_in[10];
  const float* gln  = (const float*)d_in[11];
  const float* bln  = (const float*)d_in[12];
  float* out = (float*)d_out;

  unsigned short* A   = (unsigned short*)d_ws;                          // 33.5 MB bf16
  unsigned short* woT = (unsigned short*)((char*)d_ws + (48u << 20));   // 256 KB bf16

  k0_woT<<<16, 256, 0, stream>>>(wo, woT);
  k1_contract<<<2048, 256, 0, stream>>>(fp, feat, ep, w1, b1, g1, be1, w2, b2, A);
  k2_gemm_ln<<<1024, 256, 0, stream>>>(A, woT, bwo, gln, bln, out);
}

// Round 6
// 439.796 us; speedup vs baseline: 2.0705x; 2.0705x over previous
//
#include <hip/hip_runtime.h>
#include <hip/hip_bf16.h>

#define KP    32
#define NIN_  64
#define RNK   16
#define NOUT_ 128
#define HID_  64
#define CDIM  1024   // RNK*NIN_
#define EPS_  1e-7f
#define LNEPS 1e-5f
#define NTOT  16384  // B*N

using short8 = __attribute__((ext_vector_type(8))) short;
using f32x4  = __attribute__((ext_vector_type(4))) float;

__device__ __forceinline__ unsigned short f2bf(float x) {
  unsigned u = __float_as_uint(x);
  return (unsigned short)((u + 0x7fffu + ((u >> 16) & 1u)) >> 16);
}

// ---------------- prep: woT[n][k] = bf16(wo[k][n]) ----------------
__global__ __launch_bounds__(256) void k0_woT(const float* __restrict__ wo,
                                              unsigned short* __restrict__ woT) {
  __shared__ unsigned short S[64][129];
  const int t = threadIdx.x;
  const int k0 = blockIdx.x * 64;
  #pragma unroll
  for (int i = 0; i < 32; ++i) {
    const int idx = i * 256 + t;
    const int k = idx >> 7, n = idx & 127;
    S[k][n] = f2bf(wo[(long)(k0 + k) * NOUT_ + n]);
  }
  __syncthreads();
  #pragma unroll
  for (int i = 0; i < 32; ++i) {
    const int idx = i * 256 + t;
    const int n = idx >> 6, k = idx & 63;
    woT[(long)n * CDIM + k0 + k] = S[k][n];
  }
}

// ---------------- k1: geometry + MLPs (VALU) + contraction (MFMA) ----------
// 256 thr = 4 waves, each wave 2 points (grid 2048), wave-synchronous (no
// barriers in the point loop; per-wave LDS regions, DS pipe in-order/wave).
// Phases A-C lane layout: lane = 2*kk + hh. Phase D: 4x MFMA 16x16x32.
// Feat is loaded ONLY in phase D (chunked, unroll 1) to keep VGPRs low.
__global__ __launch_bounds__(256) void k1_contract(
    const float* __restrict__ fp,   // (NTOT, KP, 3)
    const float* __restrict__ feat, // (NTOT, KP, NIN_)
    const float* __restrict__ ep,   // (NTOT, 3)
    const float* __restrict__ w1,   // (8, HID_)
    const float* __restrict__ b1, const float* __restrict__ g1,
    const float* __restrict__ be1,
    const float* __restrict__ w2,   // (HID_, RNK)
    const float* __restrict__ b2,
    unsigned short* __restrict__ A) // (NTOT, CDIM) bf16
{
  __shared__ float w1T[64][8];           // w1T[h][x] = w1[x][h]
  __shared__ float w2S[64][16];
  __shared__ float b1S[64], g1S[64], beS[64], b2S[16];
  __shared__ __align__(16) unsigned short featT[4][64 * 40]; // [wv][i*40+k] swz
  __shared__ __align__(16) unsigned short kernT[4][16 * 40]; // [wv][r*40+k] swz

  const int t = threadIdx.x;
  const int wv = t >> 6, lane = t & 63;
  const int hh = lane & 1, kk = lane >> 1;

  if (t < 64) {
    #pragma unroll
    for (int x = 0; x < 8; ++x) w1T[t][x] = w1[x * HID_ + t];
    b1S[t] = b1[t]; g1S[t] = g1[t]; beS[t] = be1[t];
  }
  reinterpret_cast<float4*>(&w2S[0][0])[t] = reinterpret_cast<const float4*>(w2)[t];
  if (t < 16) b2S[t] = b2[t];
  __syncthreads();

  #pragma unroll 1
  for (int pi = 0; pi < 2; ++pi) {
    const long pt = (long)blockIdx.x * 8 + wv * 2 + pi;

    // ---- phase A: geometry for neighbor kk (lane pairs redundant) ----
    const float* prp = fp + (pt * KP + kk) * 3;
    const float prx = prp[0], pry = prp[1], prz = prp[2];
    const float* psp = ep + pt * 3;
    const float psx = psp[0], psy = psp[1], psz = psp[2];

    float sx = prx, sy = pry, sz = prz;
    #pragma unroll
    for (int m = 2; m <= 32; m <<= 1) {
      sx += __shfl_xor(sx, m); sy += __shfl_xor(sy, m); sz += __shfl_xor(sz, m);
    }
    const float inv = 1.f / 32.f;
    const float mx = sx * inv, my = sy * inv, mz = sz * inv;

    const float l1x = mx - prx, l1y = my - pry, l1z = mz - prz;
    const float l2x = prx - psx, l2y = pry - psy, l2z = prz - psz;
    const float l3x = psx - mx, l3y = psy - my, l3z = psz - mz;
    const float l1n = sqrtf(l1x * l1x + l1y * l1y + l1z * l1z);
    const float l2n = sqrtf(l2x * l2x + l2y * l2y + l2z * l2z);
    const float l3n = sqrtf(l3x * l3x + l3y * l3y + l3z * l3z);
    const float th1 = (l1x * l2x + l1y * l2y + l1z * l2z) / (l1n * l2n + EPS_);
    const float th2 = (l2x * l3x + l2y * l3y + l2z * l3z) / (l2n * l3n + EPS_);
    const float th3 = (l3x * l1x + l3y * l1y + l3z * l1z) / (l3n * l1n + EPS_);
    const float hn  = sqrtf(prx * prx + pry * pry + prz * prz);
    const float psn = sqrtf(psx * psx + psy * psy + psz * psz);
    float cc = (psx * prx + psy * pry + psz * prz) / (psn * hn);
    cc = fminf(1.f, fmaxf(-1.f, cc));
    const float ri0 = acosf(cc) * 0.31830988618379067f;
    const float ri1 = hn,  ri2 = l1n, ri3 = l2n;
    const float ri4 = l3n, ri5 = th1, ri6 = th2, ri7 = th3;

    // ---- phase B: vals = relu(LN(ri @ w1 + b1)), lane-pair LN over 64 ----
    float vals[32];
    #pragma unroll
    for (int j = 0; j < 32; ++j) {
      const int h = hh * 32 + j;
      const float4 wa = *reinterpret_cast<const float4*>(&w1T[h][0]);
      const float4 wb = *reinterpret_cast<const float4*>(&w1T[h][4]);
      vals[j] = b1S[h]
        + ri0 * wa.x + ri1 * wa.y + ri2 * wa.z + ri3 * wa.w
        + ri4 * wb.x + ri5 * wb.y + ri6 * wb.z + ri7 * wb.w;
    }
    float s = 0.f;
    #pragma unroll
    for (int j = 0; j < 32; ++j) s += vals[j];
    s += __shfl_xor(s, 1);
    const float mu = s * (1.f / 64.f);
    float v2 = 0.f;
    #pragma unroll
    for (int j = 0; j < 32; ++j) { const float d = vals[j] - mu; v2 += d * d; }
    v2 += __shfl_xor(v2, 1);
    const float rstd = rsqrtf(v2 * (1.f / 64.f) + LNEPS);
    #pragma unroll
    for (int j = 0; j < 32; ++j) {
      const int h = hh * 32 + j;
      vals[j] = fmaxf((vals[j] - mu) * rstd * g1S[h] + beS[h], 0.f);
    }

    // ---- phase C: kern[r] = b2[r] + sum_h hdn[h]*w2[h][r] ----
    float kern[16];
    #pragma unroll
    for (int r = 0; r < 16; ++r) kern[r] = 0.f;
    #pragma unroll
    for (int j = 0; j < 32; ++j) {
      const int h = hh * 32 + j;
      const float hv = vals[j];
      #pragma unroll
      for (int rc = 0; rc < 4; ++rc) {
        const float4 wr = *reinterpret_cast<const float4*>(&w2S[h][rc * 4]);
        kern[rc * 4 + 0] += hv * wr.x;
        kern[rc * 4 + 1] += hv * wr.y;
        kern[rc * 4 + 2] += hv * wr.z;
        kern[rc * 4 + 3] += hv * wr.w;
      }
    }
    #pragma unroll
    for (int r = 0; r < 16; ++r) kern[r] += __shfl_xor(kern[r], 1);

    // write kernT[r][kk] bf16 (lane 2kk+hh writes r = hh*8+q)
    #pragma unroll
    for (int q = 0; q < 8; ++q) {
      const int r = hh * 8 + q;
      const int byte = r * 80 + ((((kk >> 3) ^ ((r >> 2) & 3)) << 4)) + (kk & 7) * 2;
      *reinterpret_cast<unsigned short*>(
          reinterpret_cast<char*>(&kernT[wv][0]) + byte) = f2bf(kern[r] + b2S[r]);
    }

    // ---- phase D-1: feat load+pack, chunked to cap register pressure ----
    // lane owns feat column i = lane; chunk c covers k = 8c..8c+7
    const float* fcol = feat + pt * (KP * NIN_) + lane;
    #pragma unroll 1
    for (int c = 0; c < 4; ++c) {
      float f[8];
      #pragma unroll
      for (int j = 0; j < 8; ++j) f[j] = fcol[(8 * c + j) * 64];
      unsigned pk0 = (unsigned)f2bf(f[0]) | ((unsigned)f2bf(f[1]) << 16);
      unsigned pk1 = (unsigned)f2bf(f[2]) | ((unsigned)f2bf(f[3]) << 16);
      unsigned pk2 = (unsigned)f2bf(f[4]) | ((unsigned)f2bf(f[5]) << 16);
      unsigned pk3 = (unsigned)f2bf(f[6]) | ((unsigned)f2bf(f[7]) << 16);
      const int byte = lane * 80 + ((c ^ ((lane >> 2) & 3)) << 4);
      *reinterpret_cast<uint4*>(reinterpret_cast<char*>(&featT[wv][0]) + byte) =
          make_uint4(pk0, pk1, pk2, pk3);
    }

    // ---- phase D-2: cont[r][i] via 4x MFMA (K=32 per instruction) ----
    const int g = lane >> 4, c16 = lane & 15;
    const short8 afr = *reinterpret_cast<const short8*>(
        reinterpret_cast<const char*>(&kernT[wv][0]) +
        c16 * 80 + ((g ^ ((c16 >> 2) & 3)) << 4));
    f32x4 acc[4];
    #pragma unroll
    for (int nt = 0; nt < 4; ++nt) {
      const int i = nt * 16 + c16;
      const short8 bfr = *reinterpret_cast<const short8*>(
          reinterpret_cast<const char*>(&featT[wv][0]) +
          i * 80 + ((g ^ ((i >> 2) & 3)) << 4));
      acc[nt] = __builtin_amdgcn_mfma_f32_16x16x32_bf16(
          afr, bfr, (f32x4){0.f, 0.f, 0.f, 0.f}, 0, 0, 0);
    }

    // ---- phase D-3: coalesced A write via per-wave LDS staging ----
    // outS overlays featT[wv] (dead after MFMA; DS pipe is in-order per wave).
    // outS row stride 68 ushorts (136B) to spread banks.
    {
      unsigned short* outS = &featT[wv][0];
      #pragma unroll
      for (int nt = 0; nt < 4; ++nt)
        #pragma unroll
        for (int reg = 0; reg < 4; ++reg)
          outS[(4 * g + reg) * 68 + nt * 16 + c16] = f2bf(acc[nt][reg]);
      const int row = lane >> 2, chunk = lane & 3;
      const uint4 v0 = *reinterpret_cast<const uint4*>(&outS[row * 68 + chunk * 16]);
      const uint4 v1 = *reinterpret_cast<const uint4*>(&outS[row * 68 + chunk * 16 + 8]);
      unsigned short* Ap = A + pt * CDIM + row * 64 + chunk * 16;
      *reinterpret_cast<uint4*>(Ap) = v0;
      *reinterpret_cast<uint4*>(Ap + 8) = v1;
    }
  }
}

// ---------------- k2: register-direct bf16 MFMA GEMM + bias + LN ------------
// BM=16, grid 1024 (4 blocks/CU). No K-loop LDS: A/B frags straight from
// global (woT = 256 KB, L2-resident). LN epilogue via small Cs.
__global__ __launch_bounds__(256) void k2_gemm_ln(
    const unsigned short* __restrict__ A,    // (NTOT, CDIM) bf16
    const unsigned short* __restrict__ woT,  // (NOUT_, CDIM) bf16
    const float* __restrict__ bwo, const float* __restrict__ gln,
    const float* __restrict__ bln, float* __restrict__ out)
{
  __shared__ float Cs[16 * 132];

  const int t = threadIdx.x;
  const int w = t >> 6, l = t & 63;
  const int m = l & 15, g = l >> 4;
  const long row0 = (long)blockIdx.x * 16;

  const unsigned short* Arow  = A   + (row0 + m) * CDIM + g * 8;
  const unsigned short* Brow0 = woT + (long)(w * 32 +      m) * CDIM + g * 8;
  const unsigned short* Brow1 = woT + (long)(w * 32 + 16 + m) * CDIM + g * 8;

  f32x4 acc0 = {0.f, 0.f, 0.f, 0.f}, acc1 = {0.f, 0.f, 0.f, 0.f};
  #pragma unroll 4
  for (int kb = 0; kb < CDIM; kb += 32) {
    const short8 af = *reinterpret_cast<const short8*>(Arow + kb);
    const short8 b0 = *reinterpret_cast<const short8*>(Brow0 + kb);
    const short8 b1v = *reinterpret_cast<const short8*>(Brow1 + kb);
    acc0 = __builtin_amdgcn_mfma_f32_16x16x32_bf16(af, b0, acc0, 0, 0, 0);
    acc1 = __builtin_amdgcn_mfma_f32_16x16x32_bf16(af, b1v, acc1, 0, 0, 0);
  }

  // scatter: D col = l&15 (n offset), row = 4g+reg (m)
  #pragma unroll
  for (int reg = 0; reg < 4; ++reg) {
    Cs[(4 * g + reg) * 132 + w * 32 +      m] = acc0[reg];
    Cs[(4 * g + reg) * 132 + w * 32 + 16 + m] = acc1[reg];
  }
  __syncthreads();

  // LN over 128 cols: 16 threads per row, 8 cols each
  {
    const int row = t >> 4, q = t & 15;
    float4 v[2];
    #pragma unroll
    for (int i = 0; i < 2; ++i) {
      const float4 cv = *reinterpret_cast<const float4*>(&Cs[row * 132 + q * 8 + i * 4]);
      const float4 bv = *reinterpret_cast<const float4*>(&bwo[q * 8 + i * 4]);
      v[i] = make_float4(cv.x + bv.x, cv.y + bv.y, cv.z + bv.z, cv.w + bv.w);
    }
    float s = v[0].x + v[0].y + v[0].z + v[0].w + v[1].x + v[1].y + v[1].z + v[1].w;
    s += __shfl_xor(s, 1); s += __shfl_xor(s, 2);
    s += __shfl_xor(s, 4); s += __shfl_xor(s, 8);
    const float mu = s * (1.f / 128.f);
    float d2 = 0.f;
    #pragma unroll
    for (int i = 0; i < 2; ++i) {
      const float dx = v[i].x - mu, dy = v[i].y - mu, dz = v[i].z - mu, dw = v[i].w - mu;
      d2 += dx * dx + dy * dy + dz * dz + dw * dw;
    }
    d2 += __shfl_xor(d2, 1); d2 += __shfl_xor(d2, 2);
    d2 += __shfl_xor(d2, 4); d2 += __shfl_xor(d2, 8);
    const float rstd = rsqrtf(d2 * (1.f / 128.f) + LNEPS);
    float* op = out + (row0 + row) * NOUT_ + q * 8;
    #pragma unroll
    for (int i = 0; i < 2; ++i) {
      const float4 gv = *reinterpret_cast<const float4*>(&gln[q * 8 + i * 4]);
      const float4 bv = *reinterpret_cast<const float4*>(&bln[q * 8 + i * 4]);
      float4 o;
      o.x = (v[i].x - mu) * rstd * gv.x + bv.x;
      o.y = (v[i].y - mu) * rstd * gv.y + bv.y;
      o.z = (v[i].z - mu) * rstd * gv.z + bv.z;
      o.w = (v[i].w - mu) * rstd * gv.w + bv.w;
      *reinterpret_cast<float4*>(op + i * 4) = o;
    }
  }
}

extern "C" void kernel_launch(void* const* d_in, const int* in_sizes, int n_in,
                              void* d_out, int out_size, void* d_ws, size_t ws_size,
                              hipStream_t stream) {
  const float* fp   = (const float*)d_in[0];
  const float* feat = (const float*)d_in[1];
  const float* ep   = (const float*)d_in[2];
  const float* w1   = (const float*)d_in[3];
  const float* b1   = (const float*)d_in[4];
  const float* g1   = (const float*)d_in[5];
  const float* be1  = (const float*)d_in[6];
  const float* w2   = (const float*)d_in[7];
  const float* b2   = (const float*)d_in[8];
  const float* wo   = (const float*)d_in[9];
  const float* bwo  = (const float*)d_in[10];
  const float* gln  = (const float*)d_in[11];
  const float* bln  = (const float*)d_in[12];
  float* out = (float*)d_out;

  unsigned short* A   = (unsigned short*)d_ws;                          // 33.5 MB bf16
  unsigned short* woT = (unsigned short*)((char*)d_ws + (48u << 20));   // 256 KB bf16

  k0_woT<<<16, 256, 0, stream>>>(wo, woT);
  k1_contract<<<2048, 256, 0, stream>>>(fp, feat, ep, w1, b1, g1, be1, w2, b2, A);
  k2_gemm_ln<<<1024, 256, 0, stream>>>(A, woT, bwo, gln, bln, out);
}